// Round 1
// baseline (694.141 us; speedup 1.0000x reference)
//
#include <hip/hip_runtime.h>

typedef unsigned short u16;
typedef unsigned int   u32;
typedef __bf16 bf16x8 __attribute__((ext_vector_type(8)));
typedef float  f32x4  __attribute__((ext_vector_type(4)));

__device__ __forceinline__ u16 f2bf(float f){
  u32 u = __float_as_uint(f);
  u32 r = (u + 0x7FFFu + ((u >> 16) & 1u)) >> 16;   // RNE
  return (u16)r;
}

// ---------------------------------------------------------------------------
// Pass 1: row sums of A (f32) fused with A -> bf16 conversion (unscaled).
// ds[i] = (sum_j A[i][j])^-1/2
// ---------------------------------------------------------------------------
__global__ __launch_bounds__(256) void rowsum_convert(
    const float* __restrict__ A, u16* __restrict__ Ab, float* __restrict__ ds){
  const int row = blockIdx.x, t = threadIdx.x;
  const float* ar = A + (size_t)row * 8192;
  u16* br = Ab + (size_t)row * 8192;
  float s = 0.f;
  #pragma unroll
  for (int j = 0; j < 8; ++j){
    int c = j * 256 + t;                    // float4 index, coalesced
    float4 v = ((const float4*)ar)[c];
    s += (v.x + v.y) + (v.z + v.w);
    ushort4 o;
    o.x = f2bf(v.x); o.y = f2bf(v.y); o.z = f2bf(v.z); o.w = f2bf(v.w);
    ((ushort4*)br)[c] = o;
  }
  #pragma unroll
  for (int off = 32; off > 0; off >>= 1) s += __shfl_down(s, off, 64);
  __shared__ float red[4];
  if ((t & 63) == 0) red[t >> 6] = s;
  __syncthreads();
  if (t == 0) ds[row] = rsqrtf(red[0] + red[1] + red[2] + red[3]);
}

// ---------------------------------------------------------------------------
// Small feature GEMM: Vt[o][i] = bf16( ds[i] * sum_k in[i][k] * W[k][o] )
// in: [8192][K] (f32 or bf16 row-major), W: [K][F] f32, out transposed [F][8192].
// 256 threads; thread t -> col o = t%F, row-group g = t/F; 16 rows/thread.
// ---------------------------------------------------------------------------
template<int K, int F, bool INBF16>
__global__ __launch_bounds__(256) void small_gemm(
    const void* __restrict__ inp, const float* __restrict__ W,
    const float* __restrict__ ds, u16* __restrict__ Vt){
  constexpr int G   = 256 / F;     // 1 (F=256) or 2 (F=128)
  constexpr int RPB = 16 * G;      // rows per block
  __shared__ float xs[RPB * K];
  const int t  = threadIdx.x;
  const int r0 = blockIdx.x * RPB;
  if constexpr (INBF16){
    const u16* ip = (const u16*)inp + (size_t)r0 * K;
    constexpr int IT = (RPB * K) / (256 * 8);
    #pragma unroll
    for (int j = 0; j < IT; ++j){
      int c = j * 256 + t;
      uint4 v = ((const uint4*)ip)[c];
      float* xp = xs + c * 8;
      xp[0] = __uint_as_float((v.x & 0xFFFFu) << 16);
      xp[1] = __uint_as_float(v.x & 0xFFFF0000u);
      xp[2] = __uint_as_float((v.y & 0xFFFFu) << 16);
      xp[3] = __uint_as_float(v.y & 0xFFFF0000u);
      xp[4] = __uint_as_float((v.z & 0xFFFFu) << 16);
      xp[5] = __uint_as_float(v.z & 0xFFFF0000u);
      xp[6] = __uint_as_float((v.w & 0xFFFFu) << 16);
      xp[7] = __uint_as_float(v.w & 0xFFFF0000u);
    }
  } else {
    const float* ip = (const float*)inp + (size_t)r0 * K;
    constexpr int IT = (RPB * K) / (256 * 4);
    #pragma unroll
    for (int j = 0; j < IT; ++j){
      int c = j * 256 + t;
      ((float4*)xs)[c] = ((const float4*)ip)[c];
    }
  }
  __syncthreads();
  const int o = t % F, g = t / F;
  float acc[16];
  #pragma unroll
  for (int r = 0; r < 16; ++r) acc[r] = 0.f;
  const float* xr = xs + g * 16 * K;
  for (int k = 0; k < K; k += 4){
    float w0 = W[(k+0)*F + o];   // coalesced across threads
    float w1 = W[(k+1)*F + o];
    float w2 = W[(k+2)*F + o];
    float w3 = W[(k+3)*F + o];
    #pragma unroll
    for (int r = 0; r < 16; ++r){
      float4 xv = *(const float4*)(xr + r*K + k);   // LDS broadcast
      acc[r] += xv.x*w0 + xv.y*w1 + xv.z*w2 + xv.w*w3;
    }
  }
  const int rb = r0 + g * 16;
  union { u16 u[16]; uint4 v[2]; } pk;
  #pragma unroll
  for (int r = 0; r < 16; ++r) pk.u[r] = f2bf(acc[r] * ds[rb + r]);
  uint4* dst = (uint4*)(Vt + (size_t)o * 8192 + rb);  // 32B contiguous/thread
  dst[0] = pk.v[0];
  dst[1] = pk.v[1];
}

// ---------------------------------------------------------------------------
// Big GEMM: out[i][o] = ds[i] * sum_j Ab[i][j] * Vt[o][j]   (+ optional relu)
// M-tile 32, full N=F, K=8192, BK=64. 256 blocks x 512 threads (8 waves).
// A tile: LDS double-buffered via global_load_lds(16B), XOR-swizzled source.
// B frags: direct global loads (zero intra-block reuse -> no LDS staging).
// ---------------------------------------------------------------------------
template<int F, bool RELU, bool OUTF32>
__global__ __launch_bounds__(512) void big_gemm(
    const u16* __restrict__ Ab, const u16* __restrict__ Vt,
    const float* __restrict__ ds, u16* __restrict__ Hout, float* __restrict__ Fout){
  constexpr int NB = F / 128;              // n-frags per wave (2 or 1)
  __shared__ u16 As[2][32 * 64];
  const int t = threadIdx.x;
  const int wave = t >> 6, lane = t & 63;
  const int row0 = blockIdx.x * 32;
  // A staging: threads 0..255 each fetch 16B; source column pre-swizzled so
  // that a linear LDS dest + swizzled ds_read is conflict-free (rule 21).
  const int ts  = t & 255;
  const int sr  = ts >> 3;                           // tile row 0..31
  const int scb = ((ts & 7) << 4) ^ ((sr & 7) << 4); // swizzled byte-col 0..127
  const u16* asrc = Ab + (size_t)(row0 + sr) * 8192 + (scb >> 1);
  // B fragment bases: col = colw + n*16 + (lane&15), k within 32: (lane>>4)*8
  const int colw  = wave * (F / 8);
  const int klane = (lane >> 4) * 8;
  size_t bbase[NB];
  #pragma unroll
  for (int n = 0; n < NB; ++n)
    bbase[n] = (size_t)(colw + n*16 + (lane & 15)) * 8192 + klane;
  const int arow = lane & 15;
  const int axor = (lane & 7) << 4;

  f32x4 acc[2][NB];
  #pragma unroll
  for (int m = 0; m < 2; ++m)
    #pragma unroll
    for (int n = 0; n < NB; ++n)
      acc[m][n] = (f32x4){0.f, 0.f, 0.f, 0.f};

  bf16x8 bA[NB][2], bB[NB][2];

  auto stageA = [&](int buf, int kt){
    if (t < 256){
      __builtin_amdgcn_global_load_lds(
        (const __attribute__((address_space(1))) u32*)(asrc + (size_t)kt * 64),
        (__attribute__((address_space(3))) u32*)(&As[buf][ts * 8]),
        16, 0, 0);
    }
  };
  auto loadB = [&](bf16x8 (&bb)[NB][2], int kt){
    #pragma unroll
    for (int n = 0; n < NB; ++n)
      #pragma unroll
      for (int kk = 0; kk < 2; ++kk)
        bb[n][kk] = *(const bf16x8*)(const void*)(Vt + bbase[n] + (size_t)kt*64 + kk*32);
  };
  auto computeT = [&](int buf, bf16x8 (&bb)[NB][2]){
    bf16x8 afr[2][2];
    #pragma unroll
    for (int m = 0; m < 2; ++m)
      #pragma unroll
      for (int kk = 0; kk < 2; ++kk){
        int off = (m*16 + arow) * 128 + (((kk*64) + ((lane >> 4) << 4)) ^ axor);
        afr[m][kk] = *(const bf16x8*)(const void*)((const char*)(&As[buf][0]) + off);
      }
    #pragma unroll
    for (int m = 0; m < 2; ++m)
      #pragma unroll
      for (int n = 0; n < NB; ++n)
        #pragma unroll
        for (int kk = 0; kk < 2; ++kk)
          acc[m][n] = __builtin_amdgcn_mfma_f32_16x16x32_bf16(
                        afr[m][kk], bb[n][kk], acc[m][n], 0, 0, 0);
  };

  stageA(0, 0);
  loadB(bA, 0);
  __syncthreads();
  for (int kt = 0; kt < 128; kt += 2){
    stageA(1, kt + 1);
    loadB(bB, kt + 1);
    computeT(0, bA);
    __syncthreads();
    if (kt < 126){
      stageA(0, kt + 2);
      loadB(bA, kt + 2);
    }
    computeT(1, bB);
    __syncthreads();
  }
  // epilogue: D row = (lane>>4)*4 + j, col = lane&15 (m89-verified layout)
  #pragma unroll
  for (int m = 0; m < 2; ++m){
    const int rbase = row0 + m*16 + ((lane >> 4) << 2);
    #pragma unroll
    for (int n = 0; n < NB; ++n){
      const int col = colw + n*16 + (lane & 15);
      #pragma unroll
      for (int j = 0; j < 4; ++j){
        const int row = rbase + j;
        float v = acc[m][n][j] * ds[row];
        if (RELU) v = fmaxf(v, 0.f);
        if (OUTF32) Fout[(size_t)row * F + col] = v;
        else        Hout[(size_t)row * F + col] = f2bf(v);
      }
    }
  }
}

// ---------------------------------------------------------------------------
// Attention scores: sc[i] = tanh(Z[i,:] @ Wl^T + bl) @ q + b
// Wl staged in exactly-64KB LDS with chunk-XOR swizzle (avoids 64-way bank hit).
// ---------------------------------------------------------------------------
__device__ __forceinline__ float tanh_fast(float x){
  x = fminf(fmaxf(x, -15.f), 15.f);
  float e = __expf(2.f * x);
  return (e - 1.f) / (e + 1.f);
}

__global__ __launch_bounds__(256) void attn_scores(
    const float* __restrict__ Z, const float* __restrict__ Wl,
    const float* __restrict__ bl, const float* __restrict__ q,
    const float* __restrict__ bsc, float* __restrict__ sc){
  __shared__ float wl[128 * 128];          // 64 KiB exactly, swizzled
  const int t = threadIdx.x, lane = t & 63, wave = t >> 6;
  for (int j = 0; j < 64; ++j){
    int idx = j * 256 + t;                 // coalesced
    int o = idx >> 7, k = idx & 127;
    int c = k >> 2, e = k & 3;
    wl[o * 128 + (((c ^ (o & 31)) << 2) | e)] = Wl[idx];
  }
  __syncthreads();
  const float bl0 = bl[lane], bl1 = bl[lane + 64];
  const float q0  = q[lane],  q1  = q[lane + 64];
  const float bb  = bsc[0];
  const int r0 = blockIdx.x * 16;
  for (int rr = 0; rr < 4; ++rr){
    int r = r0 + wave * 4 + rr;
    float d0 = 0.f, d1 = 0.f;
    #pragma unroll
    for (int c = 0; c < 32; ++c){
      float4 zv = *(const float4*)(Z + (size_t)r * 128 + c * 4);  // uniform
      float4 w0 = *(const float4*)&wl[ lane      * 128 + ((c ^ (lane & 31)) << 2)];
      float4 w1 = *(const float4*)&wl[(lane + 64)* 128 + ((c ^ (lane & 31)) << 2)];
      d0 += zv.x*w0.x + zv.y*w0.y + zv.z*w0.z + zv.w*w0.w;
      d1 += zv.x*w1.x + zv.y*w1.y + zv.z*w1.z + zv.w*w1.w;
    }
    float s = tanh_fast(d0 + bl0) * q0 + tanh_fast(d1 + bl1) * q1;
    #pragma unroll
    for (int off = 32; off > 0; off >>= 1) s += __shfl_down(s, off, 64);
    if (lane == 0) sc[r] = s + bb;
  }
}

__global__ __launch_bounds__(1024) void softmax_red(
    const float* __restrict__ sc, float* __restrict__ sred){
  const int t = threadIdx.x, lane = t & 63, wave = t >> 6;
  __shared__ float red[16];
  float m = -1e30f;
  for (int i = t; i < 8192; i += 1024) m = fmaxf(m, sc[i]);
  #pragma unroll
  for (int off = 32; off > 0; off >>= 1) m = fmaxf(m, __shfl_down(m, off, 64));
  if (lane == 0) red[wave] = m;
  __syncthreads();
  if (t == 0){
    float mm = red[0];
    for (int w = 1; w < 16; ++w) mm = fmaxf(mm, red[w]);
    red[0] = mm;
  }
  __syncthreads();
  const float bmax = red[0];
  __syncthreads();
  float s = 0.f;
  for (int i = t; i < 8192; i += 1024) s += __expf(sc[i] - bmax);
  #pragma unroll
  for (int off = 32; off > 0; off >>= 1) s += __shfl_down(s, off, 64);
  if (lane == 0) red[wave] = s;
  __syncthreads();
  if (t == 0){
    float ss = 0.f;
    for (int w = 0; w < 16; ++w) ss += red[w];
    sred[0] = bmax; sred[1] = ss;
  }
}

__global__ __launch_bounds__(256) void weighted_part(
    const float* __restrict__ sc, const float* __restrict__ sred,
    const float* __restrict__ Z, float* __restrict__ part){
  const int blk = blockIdx.x, t = threadIdx.x;
  const int o = t & 127, h = t >> 7;
  const float bmax = sred[0], inv = 1.f / sred[1];
  float acc = 0.f;
  const int i0 = blk * 128;
  for (int i = i0 + h; i < i0 + 128; i += 2){
    float w = __expf(sc[i] - bmax) * inv;
    acc += w * Z[(size_t)i * 128 + o];
  }
  __shared__ float l[256];
  l[t] = acc;
  __syncthreads();
  if (h == 0) part[blk * 128 + o] = l[o] + l[o + 128];
}

__global__ __launch_bounds__(128) void final_red(
    const float* __restrict__ part, float* __restrict__ out){
  const int o = threadIdx.x;
  float s = 0.f;
  for (int b = 0; b < 64; ++b) s += part[b * 128 + o];
  out[o] = s;
}

// ---------------------------------------------------------------------------
extern "C" void kernel_launch(void* const* d_in, const int* in_sizes, int n_in,
                              void* d_out, int out_size, void* d_ws, size_t ws_size,
                              hipStream_t stream){
  const float* x  = (const float*)d_in[0];
  const float* A  = (const float*)d_in[1];
  const float* W1 = (const float*)d_in[2];
  const float* W2 = (const float*)d_in[3];
  const float* W3 = (const float*)d_in[4];
  const float* Wl = (const float*)d_in[5];
  const float* bl = (const float*)d_in[6];
  const float* q  = (const float*)d_in[7];
  const float* b  = (const float*)d_in[8];
  float* out = (float*)d_out;

  char* ws = (char*)d_ws;
  u16*   AB   = (u16*)(ws);                      // 8192*8192 bf16   (128 MiB)
  float* DS   = (float*)(ws + 134217728);        // 8192 f32
  u16*   VT   = (u16*)(ws + 134250496);          // [F][8192] bf16   (<=4 MiB)
  u16*   HB   = (u16*)(ws + 138444800);          // [8192][256] bf16 (4 MiB)
  float* SC   = (float*)(ws + 142639104);        // 8192 f32 scores
  float* PART = (float*)(ws + 142671872);        // 64*128 f32
  float* SRED = (float*)(ws + 142704640);        // {max, sumexp}

  rowsum_convert<<<8192, 256, 0, stream>>>(A, AB, DS);
  // layer 1: V1t = (ds ⊙ x@W1)^T ; H1 = relu(ds ⊙ Ab@V1t)
  small_gemm<128, 256, false><<<512, 256, 0, stream>>>(x, W1, DS, VT);
  big_gemm<256, true, false><<<256, 512, 0, stream>>>(AB, VT, DS, HB, nullptr);
  // layer 2
  small_gemm<256, 256, true><<<512, 256, 0, stream>>>(HB, W2, DS, VT);
  big_gemm<256, true, false><<<256, 512, 0, stream>>>(AB, VT, DS, HB, nullptr);
  // layer 3 -> z_context (f32, straight into d_out)
  small_gemm<256, 128, true><<<256, 256, 0, stream>>>(HB, W3, DS, VT);
  big_gemm<128, false, true><<<256, 512, 0, stream>>>(AB, VT, DS, nullptr, out);
  // attention pooling
  attn_scores<<<512, 256, 0, stream>>>(out, Wl, bl, q, b, SC);
  softmax_red<<<1, 1024, 0, stream>>>(SC, SRED);
  weighted_part<<<64, 256, 0, stream>>>(SC, SRED, out, PART);
  final_red<<<1, 128, 0, stream>>>(PART, out + 8192 * 128);
}

// Round 2
// 625.015 us; speedup vs baseline: 1.1106x; 1.1106x over previous
//
#include <hip/hip_runtime.h>

typedef unsigned short u16;
typedef unsigned int   u32;
typedef __bf16 bf16x8 __attribute__((ext_vector_type(8)));
typedef float  f32x4  __attribute__((ext_vector_type(4)));

__device__ __forceinline__ u16 f2bf(float f){
  u32 u = __float_as_uint(f);
  u32 r = (u + 0x7FFFu + ((u >> 16) & 1u)) >> 16;   // RNE
  return (u16)r;
}

// ---------------------------------------------------------------------------
// Pass 1: row sums of A (f32) fused with A -> bf16 conversion (unscaled).
// ---------------------------------------------------------------------------
__global__ __launch_bounds__(256) void rowsum_convert(
    const float* __restrict__ A, u16* __restrict__ Ab, float* __restrict__ ds){
  const int row = blockIdx.x, t = threadIdx.x;
  const float* ar = A + (size_t)row * 8192;
  u16* br = Ab + (size_t)row * 8192;
  float s = 0.f;
  #pragma unroll
  for (int j = 0; j < 8; ++j){
    int c = j * 256 + t;                    // float4 index, coalesced
    float4 v = ((const float4*)ar)[c];
    s += (v.x + v.y) + (v.z + v.w);
    ushort4 o;
    o.x = f2bf(v.x); o.y = f2bf(v.y); o.z = f2bf(v.z); o.w = f2bf(v.w);
    ((ushort4*)br)[c] = o;
  }
  #pragma unroll
  for (int off = 32; off > 0; off >>= 1) s += __shfl_down(s, off, 64);
  __shared__ float red[4];
  if ((t & 63) == 0) red[t >> 6] = s;
  __syncthreads();
  if (t == 0) ds[row] = rsqrtf(red[0] + red[1] + red[2] + red[3]);
}

// ---------------------------------------------------------------------------
// Small feature GEMM: Vt[o][i] = bf16( ds[i] * sum_k in[i][k] * W[k][o] )
// ---------------------------------------------------------------------------
template<int K, int F, bool INBF16>
__global__ __launch_bounds__(256) void small_gemm(
    const void* __restrict__ inp, const float* __restrict__ W,
    const float* __restrict__ ds, u16* __restrict__ Vt){
  constexpr int G   = 256 / F;     // 1 (F=256) or 2 (F=128)
  constexpr int RPB = 16 * G;      // rows per block
  __shared__ float xs[RPB * K];
  const int t  = threadIdx.x;
  const int r0 = blockIdx.x * RPB;
  if constexpr (INBF16){
    const u16* ip = (const u16*)inp + (size_t)r0 * K;
    constexpr int IT = (RPB * K) / (256 * 8);
    #pragma unroll
    for (int j = 0; j < IT; ++j){
      int c = j * 256 + t;
      uint4 v = ((const uint4*)ip)[c];
      float* xp = xs + c * 8;
      xp[0] = __uint_as_float((v.x & 0xFFFFu) << 16);
      xp[1] = __uint_as_float(v.x & 0xFFFF0000u);
      xp[2] = __uint_as_float((v.y & 0xFFFFu) << 16);
      xp[3] = __uint_as_float(v.y & 0xFFFF0000u);
      xp[4] = __uint_as_float((v.z & 0xFFFFu) << 16);
      xp[5] = __uint_as_float(v.z & 0xFFFF0000u);
      xp[6] = __uint_as_float((v.w & 0xFFFFu) << 16);
      xp[7] = __uint_as_float(v.w & 0xFFFF0000u);
    }
  } else {
    const float* ip = (const float*)inp + (size_t)r0 * K;
    constexpr int IT = (RPB * K) / (256 * 4);
    #pragma unroll
    for (int j = 0; j < IT; ++j){
      int c = j * 256 + t;
      ((float4*)xs)[c] = ((const float4*)ip)[c];
    }
  }
  __syncthreads();
  const int o = t % F, g = t / F;
  float acc[16];
  #pragma unroll
  for (int r = 0; r < 16; ++r) acc[r] = 0.f;
  const float* xr = xs + g * 16 * K;
  for (int k = 0; k < K; k += 4){
    float w0 = W[(k+0)*F + o];
    float w1 = W[(k+1)*F + o];
    float w2 = W[(k+2)*F + o];
    float w3 = W[(k+3)*F + o];
    #pragma unroll
    for (int r = 0; r < 16; ++r){
      float4 xv = *(const float4*)(xr + r*K + k);
      acc[r] += xv.x*w0 + xv.y*w1 + xv.z*w2 + xv.w*w3;
    }
  }
  const int rb = r0 + g * 16;
  union { u16 u[16]; uint4 v[2]; } pk;
  #pragma unroll
  for (int r = 0; r < 16; ++r) pk.u[r] = f2bf(acc[r] * ds[rb + r]);
  uint4* dst = (uint4*)(Vt + (size_t)o * 8192 + rb);
  dst[0] = pk.v[0];
  dst[1] = pk.v[1];
}

// ---------------------------------------------------------------------------
// Big GEMM, register-direct, NO barriers in the K-loop.
// out[i][o] = ds[i] * sum_j Ab[i][j] * Vt[o][j]   (+ optional relu)
//
// Grid: 256 blocks x 512 threads. Block = 32 rows x F cols, full K=8192.
// 8 waves = 4 K-splits x 2 col-halves; each wave: 32 rows x F/2 cols x K/4.
// A-frag and B-frag are K-contiguous 16B/lane -> direct global loads, the
// compiler software-pipelines freely (no syncthreads -> no vmcnt(0) drains).
// K-split partials reduced through LDS once at the end.
// ---------------------------------------------------------------------------
template<int F, bool RELU, bool OUTF32>
__global__ __launch_bounds__(512, 2) void gemm_rd(
    const u16* __restrict__ Ab, const u16* __restrict__ Vt,
    const float* __restrict__ ds, u16* __restrict__ Hout, float* __restrict__ Fout){
  constexpr int NB  = F / 32;          // n-frags per wave (8 or 4)
  constexpr int NKT = 64;              // K-steps of 32 per K-split (2048/32)
  __shared__ float red[4][32][F];      // 128 KB (F=256) / 64 KB (F=128)

  const int t = threadIdx.x, wave = t >> 6, lane = t & 63;
  const int ks = wave >> 1;            // K-split 0..3
  const int cg = wave & 1;             // column half
  const int row0 = blockIdx.x * 32;
  const int klane = (lane >> 4) * 8;   // k-offset within 32-step
  const size_t kbase = (size_t)ks * 2048 + klane;

  const u16* arow0 = Ab + (size_t)(row0 + (lane & 15)) * 8192 + kbase;
  const u16* arow1 = arow0 + (size_t)16 * 8192;
  const u16* bcol[NB];
  #pragma unroll
  for (int n = 0; n < NB; ++n)
    bcol[n] = Vt + (size_t)(cg * (F / 2) + n * 16 + (lane & 15)) * 8192 + kbase;

  f32x4 acc[2][NB];
  #pragma unroll
  for (int m = 0; m < 2; ++m)
    #pragma unroll
    for (int n = 0; n < NB; ++n)
      acc[m][n] = (f32x4){0.f, 0.f, 0.f, 0.f};

  bf16x8 aC[2], bC[NB], aN[2], bN[NB];

  auto ldA = [&](bf16x8 (&d)[2], int kt){
    d[0] = *(const bf16x8*)(const void*)(arow0 + kt * 32);
    d[1] = *(const bf16x8*)(const void*)(arow1 + kt * 32);
  };
  auto ldB = [&](bf16x8 (&d)[NB], int kt){
    #pragma unroll
    for (int n = 0; n < NB; ++n)
      d[n] = *(const bf16x8*)(const void*)(bcol[n] + kt * 32);
  };
  auto mm = [&](bf16x8 (&a)[2], bf16x8 (&b)[NB]){
    #pragma unroll
    for (int m = 0; m < 2; ++m)
      #pragma unroll
      for (int n = 0; n < NB; ++n)
        acc[m][n] = __builtin_amdgcn_mfma_f32_16x16x32_bf16(a[m], b[n], acc[m][n], 0, 0, 0);
  };

  ldA(aC, 0); ldB(bC, 0);
  for (int kt = 0; kt < NKT; kt += 2){
    ldA(aN, kt + 1); ldB(bN, kt + 1);
    mm(aC, bC);
    if (kt + 2 < NKT){ ldA(aC, kt + 2); ldB(bC, kt + 2); }
    mm(aN, bN);
  }

  // K-split reduction through LDS (one barrier total).
  #pragma unroll
  for (int m = 0; m < 2; ++m){
    const int r = m * 16 + ((lane >> 4) << 2);
    #pragma unroll
    for (int n = 0; n < NB; ++n){
      const int c = cg * (F / 2) + n * 16 + (lane & 15);
      #pragma unroll
      for (int j = 0; j < 4; ++j)
        red[ks][r + j][c] = acc[m][n][j];
    }
  }
  __syncthreads();
  constexpr int EPT = (32 * F) / 512;  // elements per thread (16 or 8)
  #pragma unroll
  for (int i = 0; i < EPT; ++i){
    const int idx = i * 512 + t;
    const int r = idx / F, c = idx % F;
    float v = red[0][r][c] + red[1][r][c] + red[2][r][c] + red[3][r][c];
    v *= ds[row0 + r];
    if (RELU) v = fmaxf(v, 0.f);
    const int row = row0 + r;
    if (OUTF32) Fout[(size_t)row * F + c] = v;
    else        Hout[(size_t)row * F + c] = f2bf(v);
  }
}

// ---------------------------------------------------------------------------
// Attention scores: sc[i] = tanh(Z[i,:] @ Wl^T + bl) @ q + b
// ---------------------------------------------------------------------------
__device__ __forceinline__ float tanh_fast(float x){
  x = fminf(fmaxf(x, -15.f), 15.f);
  float e = __expf(2.f * x);
  return (e - 1.f) / (e + 1.f);
}

__global__ __launch_bounds__(256) void attn_scores(
    const float* __restrict__ Z, const float* __restrict__ Wl,
    const float* __restrict__ bl, const float* __restrict__ q,
    const float* __restrict__ bsc, float* __restrict__ sc){
  __shared__ float wl[128 * 128];          // 64 KiB exactly, swizzled
  const int t = threadIdx.x, lane = t & 63, wave = t >> 6;
  for (int j = 0; j < 64; ++j){
    int idx = j * 256 + t;
    int o = idx >> 7, k = idx & 127;
    int c = k >> 2, e = k & 3;
    wl[o * 128 + (((c ^ (o & 31)) << 2) | e)] = Wl[idx];
  }
  __syncthreads();
  const float bl0 = bl[lane], bl1 = bl[lane + 64];
  const float q0  = q[lane],  q1  = q[lane + 64];
  const float bb  = bsc[0];
  const int r0 = blockIdx.x * 16;
  for (int rr = 0; rr < 4; ++rr){
    int r = r0 + wave * 4 + rr;
    float d0 = 0.f, d1 = 0.f;
    #pragma unroll
    for (int c = 0; c < 32; ++c){
      float4 zv = *(const float4*)(Z + (size_t)r * 128 + c * 4);
      float4 w0 = *(const float4*)&wl[ lane      * 128 + ((c ^ (lane & 31)) << 2)];
      float4 w1 = *(const float4*)&wl[(lane + 64)* 128 + ((c ^ (lane & 31)) << 2)];
      d0 += zv.x*w0.x + zv.y*w0.y + zv.z*w0.z + zv.w*w0.w;
      d1 += zv.x*w1.x + zv.y*w1.y + zv.z*w1.z + zv.w*w1.w;
    }
    float s = tanh_fast(d0 + bl0) * q0 + tanh_fast(d1 + bl1) * q1;
    #pragma unroll
    for (int off = 32; off > 0; off >>= 1) s += __shfl_down(s, off, 64);
    if (lane == 0) sc[r] = s + bb;
  }
}

__global__ __launch_bounds__(1024) void softmax_red(
    const float* __restrict__ sc, float* __restrict__ sred){
  const int t = threadIdx.x, lane = t & 63, wave = t >> 6;
  __shared__ float red[16];
  float m = -1e30f;
  for (int i = t; i < 8192; i += 1024) m = fmaxf(m, sc[i]);
  #pragma unroll
  for (int off = 32; off > 0; off >>= 1) m = fmaxf(m, __shfl_down(m, off, 64));
  if (lane == 0) red[wave] = m;
  __syncthreads();
  if (t == 0){
    float mm = red[0];
    for (int w = 1; w < 16; ++w) mm = fmaxf(mm, red[w]);
    red[0] = mm;
  }
  __syncthreads();
  const float bmax = red[0];
  __syncthreads();
  float s = 0.f;
  for (int i = t; i < 8192; i += 1024) s += __expf(sc[i] - bmax);
  #pragma unroll
  for (int off = 32; off > 0; off >>= 1) s += __shfl_down(s, off, 64);
  if (lane == 0) red[wave] = s;
  __syncthreads();
  if (t == 0){
    float ss = 0.f;
    for (int w = 0; w < 16; ++w) ss += red[w];
    sred[0] = bmax; sred[1] = ss;
  }
}

__global__ __launch_bounds__(256) void weighted_part(
    const float* __restrict__ sc, const float* __restrict__ sred,
    const float* __restrict__ Z, float* __restrict__ part){
  const int blk = blockIdx.x, t = threadIdx.x;
  const int o = t & 127, h = t >> 7;
  const float bmax = sred[0], inv = 1.f / sred[1];
  float acc = 0.f;
  const int i0 = blk * 128;
  for (int i = i0 + h; i < i0 + 128; i += 2){
    float w = __expf(sc[i] - bmax) * inv;
    acc += w * Z[(size_t)i * 128 + o];
  }
  __shared__ float l[256];
  l[t] = acc;
  __syncthreads();
  if (h == 0) part[blk * 128 + o] = l[o] + l[o + 128];
}

__global__ __launch_bounds__(128) void final_red(
    const float* __restrict__ part, float* __restrict__ out){
  const int o = threadIdx.x;
  float s = 0.f;
  for (int b = 0; b < 64; ++b) s += part[b * 128 + o];
  out[o] = s;
}

// ---------------------------------------------------------------------------
extern "C" void kernel_launch(void* const* d_in, const int* in_sizes, int n_in,
                              void* d_out, int out_size, void* d_ws, size_t ws_size,
                              hipStream_t stream){
  const float* x  = (const float*)d_in[0];
  const float* A  = (const float*)d_in[1];
  const float* W1 = (const float*)d_in[2];
  const float* W2 = (const float*)d_in[3];
  const float* W3 = (const float*)d_in[4];
  const float* Wl = (const float*)d_in[5];
  const float* bl = (const float*)d_in[6];
  const float* q  = (const float*)d_in[7];
  const float* b  = (const float*)d_in[8];
  float* out = (float*)d_out;

  char* ws = (char*)d_ws;
  u16*   AB   = (u16*)(ws);                      // 8192*8192 bf16   (128 MiB)
  float* DS   = (float*)(ws + 134217728);        // 8192 f32
  u16*   VT   = (u16*)(ws + 134250496);          // [F][8192] bf16   (<=4 MiB)
  u16*   HB   = (u16*)(ws + 138444800);          // [8192][256] bf16 (4 MiB)
  float* SC   = (float*)(ws + 142639104);        // 8192 f32 scores
  float* PART = (float*)(ws + 142671872);        // 64*128 f32
  float* SRED = (float*)(ws + 142704640);        // {max, sumexp}

  rowsum_convert<<<8192, 256, 0, stream>>>(A, AB, DS);
  // layer 1: V1t = (ds ⊙ x@W1)^T ; H1 = relu(ds ⊙ Ab@V1t)
  small_gemm<128, 256, false><<<512, 256, 0, stream>>>(x, W1, DS, VT);
  gemm_rd<256, true, false><<<256, 512, 0, stream>>>(AB, VT, DS, HB, nullptr);
  // layer 2
  small_gemm<256, 256, true><<<512, 256, 0, stream>>>(HB, W2, DS, VT);
  gemm_rd<256, true, false><<<256, 512, 0, stream>>>(AB, VT, DS, HB, nullptr);
  // layer 3 -> z_context (f32, straight into d_out)
  small_gemm<256, 128, true><<<256, 256, 0, stream>>>(HB, W3, DS, VT);
  gemm_rd<128, false, true><<<256, 512, 0, stream>>>(AB, VT, DS, nullptr, out);
  // attention pooling
  attn_scores<<<512, 256, 0, stream>>>(out, Wl, bl, q, b, SC);
  softmax_red<<<1, 1024, 0, stream>>>(SC, SRED);
  weighted_part<<<64, 256, 0, stream>>>(SC, SRED, out, PART);
  final_red<<<1, 128, 0, stream>>>(PART, out + 8192 * 128);
}